// Round 3
// baseline (361.924 us; speedup 1.0000x reference)
//
#include <hip/hip_runtime.h>
#include <math.h>

#define NN 65536        // nodes
#define NE 524288       // edges (without self loops)
#define D 128
#define ED 32
#define NEG_SLOPE 0.2f

typedef short bf16x8 __attribute__((ext_vector_type(8)));
typedef float f32x4 __attribute__((ext_vector_type(4)));
typedef unsigned short ushort_t;

__device__ __forceinline__ float leaky(float x) { return x > 0.f ? x : NEG_SLOPE * x; }
__device__ __forceinline__ float gelu_exact(float x) {
    return 0.5f * x * (1.f + erff(x * 0.70710678118654752440f));
}
__device__ __forceinline__ unsigned short bf16_rne(float x) {
    unsigned u = __float_as_uint(x);
    return (unsigned short)((u + 0x7FFFu + ((u >> 16) & 1u)) >> 16);
}
__device__ __forceinline__ void unpack8(int4 r, float* f) {
    unsigned u0 = (unsigned)r.x, u1 = (unsigned)r.y, u2 = (unsigned)r.z, u3 = (unsigned)r.w;
    f[0] = __uint_as_float(u0 << 16); f[1] = __uint_as_float(u0 & 0xFFFF0000u);
    f[2] = __uint_as_float(u1 << 16); f[3] = __uint_as_float(u1 & 0xFFFF0000u);
    f[4] = __uint_as_float(u2 << 16); f[5] = __uint_as_float(u2 & 0xFFFF0000u);
    f[6] = __uint_as_float(u3 << 16); f[7] = __uint_as_float(u3 & 0xFFFF0000u);
}

// ---------------- front: fused {ale_hist (wvec inline) | wpack} ----------------

__global__ __launch_bounds__(256) void k_front(const float* __restrict__ ea,
        const int* __restrict__ dstArr, int* __restrict__ deg,
        const float* __restrict__ We, const float* __restrict__ ae,
        const float* __restrict__ Ws, short* __restrict__ Whp, short* __restrict__ Wlp,
        float* __restrict__ ale0, float* __restrict__ ale1, float* __restrict__ ale2) {
    if (blockIdx.x >= NE / 256) {
        // ---- wpack role: pack W into MFMA fragment order, split bf16 hi/lo ----
        int t = (blockIdx.x - NE / 256) * 256 + threadIdx.x;
        if (t >= 3 * 4 * 4 * 128) return;
        int n = t & 127;
        int q = (t >> 7) & 3;
        int ks = (t >> 9) & 3;
        int l = t >> 11;
        const float* w = Ws + (size_t)l * D * D;
        size_t obase = (size_t)l * D * D + ((size_t)((ks * 4 + q) * 128) + n) * 8;
        #pragma unroll
        for (int j = 0; j < 8; ++j) {
            float x = w[(size_t)(ks * 32 + q * 8 + j) * D + n];
            unsigned short hb = bf16_rne(x);
            float hf = __uint_as_float(((unsigned)hb) << 16);
            Whp[obase + j] = (short)hb;
            Wlp[obase + j] = (short)bf16_rne(x - hf);
        }
        return;
    }
    // ---- ale role ----
    __shared__ __align__(16) float wv[3 * ED];
    int t = threadIdx.x;
    if (t < 3 * ED) {
        int l = t >> 5, k = t & 31;
        const float4* w = (const float4*)(We + (size_t)(l * ED + k) * D);
        const float4* a = (const float4*)(ae + (size_t)l * D);
        float s = 0.f;
        #pragma unroll
        for (int i = 0; i < D / 4; ++i) {
            float4 x = w[i], y = a[i];
            s += x.x * y.x + x.y * y.y + x.z * y.z + x.w * y.w;
        }
        wv[t] = s;
    }
    __syncthreads();
    int e = blockIdx.x * 256 + t;
    atomicAdd(&deg[dstArr[e]], 1);
    const float4* row = (const float4*)(ea + (size_t)e * ED);
    const float4* w0 = (const float4*)(wv);
    const float4* w1 = (const float4*)(wv + ED);
    const float4* w2 = (const float4*)(wv + 2 * ED);
    float s0 = 0.f, s1 = 0.f, s2 = 0.f;
    #pragma unroll
    for (int i = 0; i < ED / 4; ++i) {
        float4 v = row[i];
        float4 a = w0[i], b = w1[i], c = w2[i];
        s0 += v.x * a.x + v.y * a.y + v.z * a.z + v.w * a.w;
        s1 += v.x * b.x + v.y * b.y + v.z * b.z + v.w * b.w;
        s2 += v.x * c.x + v.y * c.y + v.z * c.z + v.w * c.w;
    }
    ale0[e] = s0;
    ale1[e] = s1;
    ale2[e] = s2;
}

// ---------------- scan (2 kernels) ----------------

__global__ void k_scan1(const int* __restrict__ deg, int* __restrict__ rp, int* __restrict__ bsum) {
    __shared__ int s[256];
    int t = threadIdx.x;
    int i = blockIdx.x * 256 + t;
    int v = deg[i];
    s[t] = v;
    __syncthreads();
    #pragma unroll
    for (int off = 1; off < 256; off <<= 1) {
        int x = (t >= off) ? s[t - off] : 0;
        __syncthreads();
        s[t] += x;
        __syncthreads();
    }
    rp[i] = s[t] - v;
    if (t == 255) bsum[blockIdx.x] = s[t];
}

__global__ void k_scanF(int* __restrict__ rp, const int* __restrict__ bsum, int* __restrict__ cursor) {
    __shared__ int s[256];
    int t = threadIdx.x;
    int bid = blockIdx.x;
    int v = bsum[t];
    s[t] = v;
    __syncthreads();
    #pragma unroll
    for (int off = 1; off < 256; off <<= 1) {
        int x = (t >= off) ? s[t - off] : 0;
        __syncthreads();
        s[t] += x;
        __syncthreads();
    }
    int add = (bid > 0) ? s[bid - 1] : 0;
    int i = bid * 256 + t;
    int r = rp[i] + add;
    rp[i] = r;
    cursor[i] = r;
    if (bid == 255 && t == 255) rp[NN] = NE;
}

// ---------------- aggregation node body (shared) ----------------
// 16 lanes per dst node; produces o[8] = gelu(softmax-weighted gather + bias)
// for cols l16*8 .. l16*8+7. Fast path deg<=16 with 8-deep pre-issued gathers.

__device__ __forceinline__ void aggr_node(int n, int l16, int qb,
        const ushort_t* __restrict__ hb, const float* __restrict__ als,
        const float* __restrict__ ald, const int4* __restrict__ edata,
        const int* __restrict__ rp, const float* __restrict__ bias, int lsel,
        float* o) {
    int s = rp[n], e = rp[n + 1];
    int deg = e - s;
    float aldd = ald[n];
    float alsn = als[n];
    float inv_deg = (deg > 0) ? 1.f / (float)deg : 0.f;

    int4 hvp = *(const int4*)(hb + (size_t)n * D + l16 * 8);
    float acc8[8];

    if (deg <= 16) {
        int sn0 = 0;
        float al0 = -1e30f, alev0 = 0.f;
        if (l16 < deg) {
            int4 ed = edata[s + l16];
            sn0 = ed.x;
            alev0 = __int_as_float((lsel == 0) ? ed.y : ((lsel == 1) ? ed.z : ed.w));
            al0 = leaky(als[sn0] + aldd + alev0);
        }
        float mm = al0, asum = alev0;
        #pragma unroll
        for (int off = 1; off < 16; off <<= 1) {
            mm = fmaxf(mm, __shfl_xor(mm, off));
            asum += __shfl_xor(asum, off);
        }
        float self_al = leaky(alsn + aldd + asum * inv_deg);
        mm = fmaxf(mm, self_al);
        float p0 = (l16 < deg) ? __expf(al0 - mm) : 0.f;
        float den = p0;
        #pragma unroll
        for (int off = 1; off < 16; off <<= 1) den += __shfl_xor(den, off);
        float es = __expf(self_al - mm);
        den += es;
        float inv = 1.f / den;
        float w0 = p0 * inv;       // exactly 0 for l16 >= deg
        float wself = es * inv;

        float fv[8];
        unpack8(hvp, fv);
        #pragma unroll
        for (int j = 0; j < 8; ++j) acc8[j] = wself * fv[j];

        int sA[8]; float wA[8]; int4 rb[8];
        #pragma unroll
        for (int i = 0; i < 8; ++i) { sA[i] = __shfl(sn0, qb + i); wA[i] = __shfl(w0, qb + i); }
        #pragma unroll
        for (int i = 0; i < 8; ++i) rb[i] = *(const int4*)(hb + (size_t)sA[i] * D + l16 * 8);

        int sB[8]; float wB[8]; int4 rb2[8];
        #pragma unroll
        for (int i = 0; i < 8; ++i) { sB[i] = __shfl(sn0, qb + 8 + i); wB[i] = __shfl(w0, qb + 8 + i); }
        bool more = (deg > 8);
        if (more) {
            #pragma unroll
            for (int i = 0; i < 8; ++i) rb2[i] = *(const int4*)(hb + (size_t)sB[i] * D + l16 * 8);
        }

        #pragma unroll
        for (int i = 0; i < 8; ++i) {
            float f[8];
            unpack8(rb[i], f);
            #pragma unroll
            for (int j = 0; j < 8; ++j) acc8[j] += wA[i] * f[j];
        }
        if (more) {
            #pragma unroll
            for (int i = 0; i < 8; ++i) {
                float f[8];
                unpack8(rb2[i], f);
                #pragma unroll
                for (int j = 0; j < 8; ++j) acc8[j] += wB[i] * f[j];
            }
        }
    } else {
        // general path (rare): chunked 3-pass with recompute
        float mm = -1e30f, asum = 0.f;
        for (int base = s; base < e; base += 16) {
            int j = base + l16;
            if (j < e) {
                int4 ed = edata[j];
                float alev = __int_as_float((lsel == 0) ? ed.y : ((lsel == 1) ? ed.z : ed.w));
                asum += alev;
                mm = fmaxf(mm, leaky(als[ed.x] + aldd + alev));
            }
        }
        #pragma unroll
        for (int off = 1; off < 16; off <<= 1) {
            mm = fmaxf(mm, __shfl_xor(mm, off));
            asum += __shfl_xor(asum, off);
        }
        float self_al = leaky(alsn + aldd + asum * inv_deg);
        mm = fmaxf(mm, self_al);
        float den = 0.f;
        for (int base = s; base < e; base += 16) {
            int j = base + l16;
            if (j < e) {
                int4 ed = edata[j];
                float alev = __int_as_float((lsel == 0) ? ed.y : ((lsel == 1) ? ed.z : ed.w));
                den += __expf(leaky(als[ed.x] + aldd + alev) - mm);
            }
        }
        #pragma unroll
        for (int off = 1; off < 16; off <<= 1) den += __shfl_xor(den, off);
        float es = __expf(self_al - mm);
        den += es;
        float inv = 1.f / den;
        float wself = es * inv;
        float fv[8];
        unpack8(hvp, fv);
        #pragma unroll
        for (int j = 0; j < 8; ++j) acc8[j] = wself * fv[j];
        for (int base = s; base < e; base += 16) {
            int cnt = min(e - base, 16);
            int sn = 0;
            float w = 0.f;
            if (l16 < cnt) {
                int4 ed = edata[base + l16];
                sn = ed.x;
                float alev = __int_as_float((lsel == 0) ? ed.y : ((lsel == 1) ? ed.z : ed.w));
                w = __expf(leaky(als[sn] + aldd + alev) - mm) * inv;
            }
            for (int tt = 0; tt < cnt; ++tt) {
                int st = __shfl(sn, qb + tt);
                float wt = __shfl(w, qb + tt);
                int4 r = *(const int4*)(hb + (size_t)st * D + l16 * 8);
                float f[8];
                unpack8(r, f);
                #pragma unroll
                for (int j = 0; j < 8; ++j) acc8[j] += wt * f[j];
            }
        }
    }

    const float4* b4 = (const float4*)(bias + l16 * 8);
    float4 b0 = b4[0], b1 = b4[1];
    float bb[8] = {b0.x, b0.y, b0.z, b0.w, b1.x, b1.y, b1.z, b1.w};
    #pragma unroll
    for (int j = 0; j < 8; ++j) o[j] = gelu_exact(acc8[j] + bb[j]);
}

// ---------------- k0: layer-0 GEMM (global A = x) + fused edge scatter ----------------
// Every block owns a 64-row gemm tile AND a 512-edge scatter slice; atomics
// issued before the gemm so their latency hides under MFMA (no scatter tail).

__global__ __launch_bounds__(256) void k_gemm0scat(const float* __restrict__ A,
        const short* __restrict__ Whp, const short* __restrict__ Wlp,
        const float* __restrict__ a_s, const float* __restrict__ a_d,
        ushort_t* __restrict__ Hb, float* __restrict__ als, float* __restrict__ ald,
        const int* __restrict__ srcArr, const int* __restrict__ dstArr,
        int* __restrict__ cursor, const float* __restrict__ ale0,
        const float* __restrict__ ale1, const float* __restrict__ ale2,
        int4* __restrict__ edata) {
    __shared__ int4 Bs[2048];   // 32KB: [0..1023]=hi, [1024..2047]=lo; reused for transpose
    int t = threadIdx.x;
    int wave = t >> 6, lane = t & 63;
    int l16 = lane & 15, q = lane >> 4;
    int b = blockIdx.x;
    int rows_base = b * 64 + wave * 16;

    // ---- scatter prologue: 2 edges per thread; atomics issued early ----
    int e0 = b * 512 + t, e1 = e0 + 256;
    int d0 = dstArr[e0], d1 = dstArr[e1];
    int p0 = atomicAdd(&cursor[d0], 1);
    int p1 = atomicAdd(&cursor[d1], 1);
    int s0 = srcArr[e0], s1 = srcArr[e1];
    float a00 = ale0[e0], a01 = ale1[e0], a02 = ale2[e0];
    float a10 = ale0[e1], a11 = ale1[e1], a12 = ale2[e1];

    const int4* wh4 = (const int4*)Whp;
    const int4* wl4 = (const int4*)Wlp;
    const short* bsh = (const short*)Bs;
    const short* bsl = (const short*)(Bs + 1024);

    f32x4 acc[8] = {};
    #pragma unroll
    for (int h2 = 0; h2 < 2; ++h2) {
        if (h2) __syncthreads();
        #pragma unroll
        for (int i = 0; i < 4; ++i) {
            Bs[t + 256 * i] = wh4[h2 * 1024 + t + 256 * i];
            Bs[1024 + t + 256 * i] = wl4[h2 * 1024 + t + 256 * i];
        }
        __syncthreads();
        #pragma unroll
        for (int kk = 0; kk < 2; ++kk) {
            int ks = h2 * 2 + kk;
            const float* ap = A + (size_t)(rows_base + l16) * D + ks * 32 + q * 8;
            float4 v0 = *(const float4*)ap;
            float4 v1 = *(const float4*)(ap + 4);
            float f[8] = {v0.x, v0.y, v0.z, v0.w, v1.x, v1.y, v1.z, v1.w};
            bf16x8 ah, alo;
            #pragma unroll
            for (int j = 0; j < 8; ++j) {
                unsigned short hb = bf16_rne(f[j]);
                float hf = __uint_as_float(((unsigned)hb) << 16);
                ah[j]  = (short)hb;
                alo[j] = (short)bf16_rne(f[j] - hf);
            }
            #pragma unroll
            for (int nt = 0; nt < 8; ++nt) {
                int idx = (((kk * 4 + q) * 128) + nt * 16 + l16) * 8;
                bf16x8 bh = *(const bf16x8*)(bsh + idx);
                bf16x8 bl = *(const bf16x8*)(bsl + idx);
                acc[nt] = __builtin_amdgcn_mfma_f32_16x16x32_bf16(bh, ah, acc[nt], 0, 0, 0);
                acc[nt] = __builtin_amdgcn_mfma_f32_16x16x32_bf16(bl, ah, acc[nt], 0, 0, 0);
                acc[nt] = __builtin_amdgcn_mfma_f32_16x16x32_bf16(bh, alo, acc[nt], 0, 0, 0);
            }
        }
    }

    // ---- scatter payload stores (atomic results long since landed) ----
    edata[p0] = make_int4(s0, __float_as_int(a00), __float_as_int(a01), __float_as_int(a02));
    edata[p1] = make_int4(s1, __float_as_int(a10), __float_as_int(a11), __float_as_int(a12));

    // ---- epilogue: als/ald + Hb via swizzled LDS transpose ----
    float ps = 0.f, pd = 0.f;
    #pragma unroll
    for (int nt = 0; nt < 8; ++nt) {
        float4 a4 = *(const float4*)(a_s + nt * 16 + q * 4);
        float4 d4 = *(const float4*)(a_d + nt * 16 + q * 4);
        ps += acc[nt][0] * a4.x + acc[nt][1] * a4.y + acc[nt][2] * a4.z + acc[nt][3] * a4.w;
        pd += acc[nt][0] * d4.x + acc[nt][1] * d4.y + acc[nt][2] * d4.z + acc[nt][3] * d4.w;
    }
    ps += __shfl_xor(ps, 16); pd += __shfl_xor(pd, 16);
    ps += __shfl_xor(ps, 32); pd += __shfl_xor(pd, 32);
    if (q == 0) {
        als[rows_base + l16] = ps;
        ald[rows_base + l16] = pd;
    }

    __syncthreads();
    char* tb = (char*)Bs + wave * 4096;
    {
        int row = l16;
        unsigned key = (unsigned)(row & 7) << 4;
        #pragma unroll
        for (int nt = 0; nt < 8; ++nt) {
            ushort4 pk;
            pk.x = bf16_rne(acc[nt][0]);
            pk.y = bf16_rne(acc[nt][1]);
            pk.z = bf16_rne(acc[nt][2]);
            pk.w = bf16_rne(acc[nt][3]);
            unsigned byteoff = (unsigned)row * 256u + (unsigned)(nt * 16 + q * 4) * 2u;
            *(ushort4*)(tb + (byteoff ^ key)) = pk;
        }
    }
    __syncthreads();
    #pragma unroll
    for (int i = 0; i < 4; ++i) {
        int m = lane + 64 * i;
        unsigned row = (unsigned)m >> 4;
        unsigned byteoff = (unsigned)m * 16u;
        unsigned addr = byteoff ^ ((row & 7u) << 4);
        int4 v = *(const int4*)(tb + addr);
        *(int4*)((char*)Hb + (size_t)rows_base * 256 + (size_t)m * 16) = v;
    }
}

// ---------------- k1/k2: fused aggr(l) -> gemm(l+1) ----------------
// Block = 64 nodes. Phase 1: each 16-lane group aggregates 4 nodes, writes
// gelu'd fp32 rows into a swizzled 32KB LDS A-buffer. Phase 2: split-bf16
// MFMA gemm reading A from LDS, W staged in 16KB quarters. Double-buffered
// Hb/als/ald avoid cross-block races at the dispatch boundary.

__global__ __launch_bounds__(256) void k_aggrgemm(const ushort_t* __restrict__ hb,
        const float* __restrict__ als_in, const float* __restrict__ ald_in,
        const int4* __restrict__ edata, const int* __restrict__ rp,
        const float* __restrict__ bias, int lsel,
        const short* __restrict__ Whp, const short* __restrict__ Wlp,
        const float* __restrict__ a_s, const float* __restrict__ a_d,
        ushort_t* __restrict__ Hb_out, float* __restrict__ als_out,
        float* __restrict__ ald_out) {
    __shared__ __align__(16) char Abuf[32768];   // 64 rows x 512B fp32, 16B-swizzled
    __shared__ int4 Wst[1024];                    // 16KB quarter: [0..511]=hi,[512..1023]=lo
    int t = threadIdx.x;
    int lane = t & 63;
    int l16 = lane & 15;
    int qb = lane & 48;
    int q = lane >> 4;
    int wave = t >> 6;
    int b = blockIdx.x;

    // ---- phase 1: aggregate 4 nodes per 16-lane group ----
    #pragma unroll
    for (int j = 0; j < 4; ++j) {
        int nl = (t >> 4) + 16 * j;          // local row 0..63
        int n = b * 64 + nl;
        float o[8];
        aggr_node(n, l16, qb, hb, als_in, ald_in, edata, rp, bias, lsel, o);
        unsigned key = (unsigned)(nl & 7) << 4;
        unsigned bo = (unsigned)nl * 512u + (unsigned)l16 * 32u;
        *(float4*)(Abuf + ((bo) ^ key)) = make_float4(o[0], o[1], o[2], o[3]);
        *(float4*)(Abuf + ((bo + 16) ^ key)) = make_float4(o[4], o[5], o[6], o[7]);
    }
    __syncthreads();

    // ---- phase 2: gemm, A from LDS ----
    int rows_base = b * 64 + wave * 16;
    int rl = wave * 16 + l16;                 // local row
    unsigned akey = (unsigned)(rl & 7) << 4;
    const int4* wh4 = (const int4*)Whp;
    const int4* wl4 = (const int4*)Wlp;
    const short* bsh = (const short*)Wst;
    const short* bsl = (const short*)(Wst + 512);

    f32x4 acc[8] = {};
    #pragma unroll
    for (int ks = 0; ks < 4; ++ks) {
        if (ks) __syncthreads();
        Wst[t]       = wh4[ks * 512 + t];
        Wst[t + 256] = wh4[ks * 512 + 256 + t];
        Wst[512 + t]       = wl4[ks * 512 + t];
        Wst[512 + t + 256] = wl4[ks * 512 + 256 + t];
        __syncthreads();
        unsigned abo = (unsigned)rl * 512u + (unsigned)(ks * 128 + q * 32);
        float4 v0 = *(const float4*)(Abuf + ((abo) ^ akey));
        float4 v1 = *(const float4*)(Abuf + ((abo + 16) ^ akey));
        float f[8] = {v0.x, v0.y, v0.z, v0.w, v1.x, v1.y, v1.z, v1.w};
        bf16x8 ah, alo;
        #pragma unroll
        for (int j = 0; j < 8; ++j) {
            unsigned short hb16 = bf16_rne(f[j]);
            float hf = __uint_as_float(((unsigned)hb16) << 16);
            ah[j]  = (short)hb16;
            alo[j] = (short)bf16_rne(f[j] - hf);
        }
        #pragma unroll
        for (int nt = 0; nt < 8; ++nt) {
            int idx = (q * 128 + nt * 16 + l16) * 8;
            bf16x8 bh = *(const bf16x8*)(bsh + idx);
            bf16x8 bl = *(const bf16x8*)(bsl + idx);
            acc[nt] = __builtin_amdgcn_mfma_f32_16x16x32_bf16(bh, ah, acc[nt], 0, 0, 0);
            acc[nt] = __builtin_amdgcn_mfma_f32_16x16x32_bf16(bl, ah, acc[nt], 0, 0, 0);
            acc[nt] = __builtin_amdgcn_mfma_f32_16x16x32_bf16(bh, alo, acc[nt], 0, 0, 0);
        }
    }

    // ---- epilogue: als/ald + Hb via swizzled LDS transpose (reuse Abuf) ----
    float ps = 0.f, pd = 0.f;
    #pragma unroll
    for (int nt = 0; nt < 8; ++nt) {
        float4 a4 = *(const float4*)(a_s + nt * 16 + q * 4);
        float4 d4 = *(const float4*)(a_d + nt * 16 + q * 4);
        ps += acc[nt][0] * a4.x + acc[nt][1] * a4.y + acc[nt][2] * a4.z + acc[nt][3] * a4.w;
        pd += acc[nt][0] * d4.x + acc[nt][1] * d4.y + acc[nt][2] * d4.z + acc[nt][3] * d4.w;
    }
    ps += __shfl_xor(ps, 16); pd += __shfl_xor(pd, 16);
    ps += __shfl_xor(ps, 32); pd += __shfl_xor(pd, 32);
    if (q == 0) {
        als_out[rows_base + l16] = ps;
        ald_out[rows_base + l16] = pd;
    }

    __syncthreads();                // A fully consumed; reuse Abuf for transpose
    char* tb = Abuf + wave * 4096;
    {
        int row = l16;
        unsigned key = (unsigned)(row & 7) << 4;
        #pragma unroll
        for (int nt = 0; nt < 8; ++nt) {
            ushort4 pk;
            pk.x = bf16_rne(acc[nt][0]);
            pk.y = bf16_rne(acc[nt][1]);
            pk.z = bf16_rne(acc[nt][2]);
            pk.w = bf16_rne(acc[nt][3]);
            unsigned byteoff = (unsigned)row * 256u + (unsigned)(nt * 16 + q * 4) * 2u;
            *(ushort4*)(tb + (byteoff ^ key)) = pk;
        }
    }
    __syncthreads();
    #pragma unroll
    for (int i = 0; i < 4; ++i) {
        int m = lane + 64 * i;
        unsigned row = (unsigned)m >> 4;
        unsigned byteoff = (unsigned)m * 16u;
        unsigned addr = byteoff ^ ((row & 7u) << 4);
        int4 v = *(const int4*)(tb + addr);
        *(int4*)((char*)Hb_out + (size_t)rows_base * 256 + (size_t)m * 16) = v;
    }
}

// ---------------- k3: final aggregation -> out ----------------

__global__ __launch_bounds__(256) void k_aggr_final(const ushort_t* __restrict__ hb,
        const float* __restrict__ als, const float* __restrict__ ald,
        const int4* __restrict__ edata, const int* __restrict__ rp,
        const float* __restrict__ bias, int lsel, float* __restrict__ out_f32) {
    int t = threadIdx.x;
    int lane = t & 63;
    int l16 = lane & 15;
    int qb = lane & 48;
    int n = blockIdx.x * 16 + (t >> 4);
    float o[8];
    aggr_node(n, l16, qb, hb, als, ald, edata, rp, bias, lsel, o);
    float4* o4 = (float4*)(out_f32 + (size_t)n * D + l16 * 8);
    o4[0] = make_float4(o[0], o[1], o[2], o[3]);
    o4[1] = make_float4(o[4], o[5], o[6], o[7]);
}

// ---------------- launch ----------------

extern "C" void kernel_launch(void* const* d_in, const int* in_sizes, int n_in,
                              void* d_out, int out_size, void* d_ws, size_t ws_size,
                              hipStream_t stream) {
    (void)in_sizes; (void)n_in; (void)out_size; (void)ws_size;
    const float* x        = (const float*)d_in[0];
    const int*   eidx     = (const int*)d_in[1];   // [2, NE]: row0=src, row1=dst
    const float* ea       = (const float*)d_in[2];
    const float* Ws       = (const float*)d_in[3];
    const float* att_src  = (const float*)d_in[4];
    const float* att_dst  = (const float*)d_in[5];
    const float* W_edge   = (const float*)d_in[6];
    const float* att_edge = (const float*)d_in[7];
    const float* bias     = (const float*)d_in[8];
    float* out = (float*)d_out;

    char* ws = (char*)d_ws;
    size_t off = 0;
    auto alloc = [&](size_t bytes) {
        void* p = ws + off;
        off += (bytes + 255) & ~(size_t)255;
        return p;
    };
    ushort_t* HbA  = (ushort_t*)alloc((size_t)NN * D * 2);  // bf16 h (double-buffered)
    ushort_t* HbB  = (ushort_t*)alloc((size_t)NN * D * 2);
    float*    alsA = (float*)alloc((size_t)NN * 4);
    float*    aldA = (float*)alloc((size_t)NN * 4);
    float*    alsB = (float*)alloc((size_t)NN * 4);
    float*    aldB = (float*)alloc((size_t)NN * 4);
    int4*     edata= (int4*)alloc((size_t)NE * 16);         // (src, ale0, ale1, ale2)
    float*    ale0 = (float*)alloc((size_t)NE * 4);
    float*    ale1 = (float*)alloc((size_t)NE * 4);
    float*    ale2 = (float*)alloc((size_t)NE * 4);
    int*      deg  = (int*)alloc((size_t)NN * 4);
    int*      rp   = (int*)alloc((size_t)(NN + 4) * 4);
    int*      cursor = (int*)alloc((size_t)NN * 4);
    int*      bsum = (int*)alloc(256 * 4);
    short*    Whp  = (short*)alloc((size_t)3 * D * D * 2);
    short*    Wlp  = (short*)alloc((size_t)3 * D * D * 2);

    const int* e_src = eidx;
    const int* e_dst = eidx + NE;

    // CSR build + edge precompute + weight pack (fused front)
    hipMemsetAsync(deg, 0, (size_t)NN * 4, stream);
    k_front<<<NE / 256 + 24, 256, 0, stream>>>(ea, e_dst, deg, W_edge, att_edge,
                                               Ws, Whp, Wlp, ale0, ale1, ale2);
    k_scan1<<<NN / 256, 256, 0, stream>>>(deg, rp, bsum);
    k_scanF<<<NN / 256, 256, 0, stream>>>(rp, bsum, cursor);

    // k0: layer-0 GEMM + fused scatter
    k_gemm0scat<<<NN / 64, 256, 0, stream>>>(x, Whp, Wlp, att_src, att_dst,
                                             HbA, alsA, aldA,
                                             e_src, e_dst, cursor, ale0, ale1, ale2, edata);

    // k1: aggr(L0) -> gemm(L1)
    k_aggrgemm<<<NN / 64, 256, 0, stream>>>(HbA, alsA, aldA, edata, rp, bias, 0,
                                            Whp + (size_t)1 * D * D, Wlp + (size_t)1 * D * D,
                                            att_src + D, att_dst + D,
                                            HbB, alsB, aldB);
    // k2: aggr(L1) -> gemm(L2)
    k_aggrgemm<<<NN / 64, 256, 0, stream>>>(HbB, alsB, aldB, edata, rp, bias + D, 1,
                                            Whp + (size_t)2 * D * D, Wlp + (size_t)2 * D * D,
                                            att_src + 2 * D, att_dst + 2 * D,
                                            HbA, alsA, aldA);
    // k3: final aggr -> out
    k_aggr_final<<<NN / 16, 256, 0, stream>>>(HbA, alsA, aldA, edata, rp, bias + 2 * D, 2, out);
}

// Round 4
// 351.990 us; speedup vs baseline: 1.0282x; 1.0282x over previous
//
#include <hip/hip_runtime.h>
#include <math.h>

#define NN 65536        // nodes
#define NE 524288       // edges (without self loops)
#define D 128
#define ED 32
#define NEG_SLOPE 0.2f

typedef short bf16x8 __attribute__((ext_vector_type(8)));
typedef float f32x4 __attribute__((ext_vector_type(4)));
typedef unsigned short ushort_t;

__device__ __forceinline__ float leaky(float x) { return x > 0.f ? x : NEG_SLOPE * x; }
__device__ __forceinline__ float gelu_exact(float x) {
    return 0.5f * x * (1.f + erff(x * 0.70710678118654752440f));
}
__device__ __forceinline__ unsigned short bf16_rne(float x) {
    unsigned u = __float_as_uint(x);
    return (unsigned short)((u + 0x7FFFu + ((u >> 16) & 1u)) >> 16);
}
__device__ __forceinline__ void unpack8(int4 r, float* f) {
    unsigned u0 = (unsigned)r.x, u1 = (unsigned)r.y, u2 = (unsigned)r.z, u3 = (unsigned)r.w;
    f[0] = __uint_as_float(u0 << 16); f[1] = __uint_as_float(u0 & 0xFFFF0000u);
    f[2] = __uint_as_float(u1 << 16); f[3] = __uint_as_float(u1 & 0xFFFF0000u);
    f[4] = __uint_as_float(u2 << 16); f[5] = __uint_as_float(u2 & 0xFFFF0000u);
    f[6] = __uint_as_float(u3 << 16); f[7] = __uint_as_float(u3 & 0xFFFF0000u);
}

// ---------------- front: fused {ale_hist (wvec inline) | wpack} ----------------

__global__ __launch_bounds__(256) void k_front(const float* __restrict__ ea,
        const int* __restrict__ dstArr, int* __restrict__ deg,
        const float* __restrict__ We, const float* __restrict__ ae,
        const float* __restrict__ Ws, short* __restrict__ Whp, short* __restrict__ Wlp,
        float* __restrict__ ale0, float* __restrict__ ale1, float* __restrict__ ale2) {
    if (blockIdx.x >= NE / 256) {
        // ---- wpack role: pack W into MFMA fragment order, split bf16 hi/lo ----
        int t = (blockIdx.x - NE / 256) * 256 + threadIdx.x;
        if (t >= 3 * 4 * 4 * 128) return;
        int n = t & 127;
        int q = (t >> 7) & 3;
        int ks = (t >> 9) & 3;
        int l = t >> 11;
        const float* w = Ws + (size_t)l * D * D;
        size_t obase = (size_t)l * D * D + ((size_t)((ks * 4 + q) * 128) + n) * 8;
        #pragma unroll
        for (int j = 0; j < 8; ++j) {
            float x = w[(size_t)(ks * 32 + q * 8 + j) * D + n];
            unsigned short hb = bf16_rne(x);
            float hf = __uint_as_float(((unsigned)hb) << 16);
            Whp[obase + j] = (short)hb;
            Wlp[obase + j] = (short)bf16_rne(x - hf);
        }
        return;
    }
    // ---- ale role ----
    __shared__ __align__(16) float wv[3 * ED];
    int t = threadIdx.x;
    if (t < 3 * ED) {
        int l = t >> 5, k = t & 31;
        const float4* w = (const float4*)(We + (size_t)(l * ED + k) * D);
        const float4* a = (const float4*)(ae + (size_t)l * D);
        float s = 0.f;
        #pragma unroll
        for (int i = 0; i < D / 4; ++i) {
            float4 x = w[i], y = a[i];
            s += x.x * y.x + x.y * y.y + x.z * y.z + x.w * y.w;
        }
        wv[t] = s;
    }
    __syncthreads();
    int e = blockIdx.x * 256 + t;
    atomicAdd(&deg[dstArr[e]], 1);
    const float4* row = (const float4*)(ea + (size_t)e * ED);
    const float4* w0 = (const float4*)(wv);
    const float4* w1 = (const float4*)(wv + ED);
    const float4* w2 = (const float4*)(wv + 2 * ED);
    float s0 = 0.f, s1 = 0.f, s2 = 0.f;
    #pragma unroll
    for (int i = 0; i < ED / 4; ++i) {
        float4 v = row[i];
        float4 a = w0[i], b = w1[i], c = w2[i];
        s0 += v.x * a.x + v.y * a.y + v.z * a.z + v.w * a.w;
        s1 += v.x * b.x + v.y * b.y + v.z * b.z + v.w * b.w;
        s2 += v.x * c.x + v.y * c.y + v.z * c.z + v.w * c.w;
    }
    ale0[e] = s0;
    ale1[e] = s1;
    ale2[e] = s2;
}

// ---------------- scan (2 kernels) ----------------

__global__ void k_scan1(const int* __restrict__ deg, int* __restrict__ rp, int* __restrict__ bsum) {
    __shared__ int s[256];
    int t = threadIdx.x;
    int i = blockIdx.x * 256 + t;
    int v = deg[i];
    s[t] = v;
    __syncthreads();
    #pragma unroll
    for (int off = 1; off < 256; off <<= 1) {
        int x = (t >= off) ? s[t - off] : 0;
        __syncthreads();
        s[t] += x;
        __syncthreads();
    }
    rp[i] = s[t] - v;
    if (t == 255) bsum[blockIdx.x] = s[t];
}

__global__ void k_scanF(int* __restrict__ rp, const int* __restrict__ bsum, int* __restrict__ cursor) {
    __shared__ int s[256];
    int t = threadIdx.x;
    int bid = blockIdx.x;
    int v = bsum[t];
    s[t] = v;
    __syncthreads();
    #pragma unroll
    for (int off = 1; off < 256; off <<= 1) {
        int x = (t >= off) ? s[t - off] : 0;
        __syncthreads();
        s[t] += x;
        __syncthreads();
    }
    int add = (bid > 0) ? s[bid - 1] : 0;
    int i = bid * 256 + t;
    int r = rp[i] + add;
    rp[i] = r;
    cursor[i] = r;
    if (bid == 255 && t == 255) rp[NN] = NE;
}

// ---------------- k0: layer-0 GEMM (global A = x) + fused edge scatter ----------------
// Every block owns a 64-row gemm tile AND a 512-edge scatter slice; atomics
// issued before the gemm so their latency hides under MFMA (no scatter tail).

__global__ __launch_bounds__(256) void k_gemm0scat(const float* __restrict__ A,
        const short* __restrict__ Whp, const short* __restrict__ Wlp,
        const float* __restrict__ a_s, const float* __restrict__ a_d,
        ushort_t* __restrict__ Hb, float* __restrict__ als, float* __restrict__ ald,
        const int* __restrict__ srcArr, const int* __restrict__ dstArr,
        int* __restrict__ cursor, const float* __restrict__ ale0,
        const float* __restrict__ ale1, const float* __restrict__ ale2,
        int4* __restrict__ edata) {
    __shared__ int4 Bs[2048];   // 32KB: [0..1023]=hi, [1024..2047]=lo; reused for transpose
    int t = threadIdx.x;
    int wave = t >> 6, lane = t & 63;
    int l16 = lane & 15, q = lane >> 4;
    int b = blockIdx.x;
    int rows_base = b * 64 + wave * 16;

    // ---- scatter prologue: 2 edges per thread; atomics issued early ----
    int e0 = b * 512 + t, e1 = e0 + 256;
    int d0 = dstArr[e0], d1 = dstArr[e1];
    int p0 = atomicAdd(&cursor[d0], 1);
    int p1 = atomicAdd(&cursor[d1], 1);
    int s0 = srcArr[e0], s1 = srcArr[e1];
    float a00 = ale0[e0], a01 = ale1[e0], a02 = ale2[e0];
    float a10 = ale0[e1], a11 = ale1[e1], a12 = ale2[e1];

    const int4* wh4 = (const int4*)Whp;
    const int4* wl4 = (const int4*)Wlp;
    const short* bsh = (const short*)Bs;
    const short* bsl = (const short*)(Bs + 1024);

    f32x4 acc[8] = {};
    #pragma unroll
    for (int h2 = 0; h2 < 2; ++h2) {
        if (h2) __syncthreads();
        #pragma unroll
        for (int i = 0; i < 4; ++i) {
            Bs[t + 256 * i] = wh4[h2 * 1024 + t + 256 * i];
            Bs[1024 + t + 256 * i] = wl4[h2 * 1024 + t + 256 * i];
        }
        __syncthreads();
        #pragma unroll
        for (int kk = 0; kk < 2; ++kk) {
            int ks = h2 * 2 + kk;
            const float* ap = A + (size_t)(rows_base + l16) * D + ks * 32 + q * 8;
            float4 v0 = *(const float4*)ap;
            float4 v1 = *(const float4*)(ap + 4);
            float f[8] = {v0.x, v0.y, v0.z, v0.w, v1.x, v1.y, v1.z, v1.w};
            bf16x8 ah, alo;
            #pragma unroll
            for (int j = 0; j < 8; ++j) {
                unsigned short hb = bf16_rne(f[j]);
                float hf = __uint_as_float(((unsigned)hb) << 16);
                ah[j]  = (short)hb;
                alo[j] = (short)bf16_rne(f[j] - hf);
            }
            #pragma unroll
            for (int nt = 0; nt < 8; ++nt) {
                int idx = (((kk * 4 + q) * 128) + nt * 16 + l16) * 8;
                bf16x8 bh = *(const bf16x8*)(bsh + idx);
                bf16x8 bl = *(const bf16x8*)(bsl + idx);
                acc[nt] = __builtin_amdgcn_mfma_f32_16x16x32_bf16(bh, ah, acc[nt], 0, 0, 0);
                acc[nt] = __builtin_amdgcn_mfma_f32_16x16x32_bf16(bl, ah, acc[nt], 0, 0, 0);
                acc[nt] = __builtin_amdgcn_mfma_f32_16x16x32_bf16(bh, alo, acc[nt], 0, 0, 0);
            }
        }
    }

    // ---- scatter payload stores (atomic results long since landed) ----
    edata[p0] = make_int4(s0, __float_as_int(a00), __float_as_int(a01), __float_as_int(a02));
    edata[p1] = make_int4(s1, __float_as_int(a10), __float_as_int(a11), __float_as_int(a12));

    // ---- epilogue: als/ald + Hb via swizzled LDS transpose ----
    float ps = 0.f, pd = 0.f;
    #pragma unroll
    for (int nt = 0; nt < 8; ++nt) {
        float4 a4 = *(const float4*)(a_s + nt * 16 + q * 4);
        float4 d4 = *(const float4*)(a_d + nt * 16 + q * 4);
        ps += acc[nt][0] * a4.x + acc[nt][1] * a4.y + acc[nt][2] * a4.z + acc[nt][3] * a4.w;
        pd += acc[nt][0] * d4.x + acc[nt][1] * d4.y + acc[nt][2] * d4.z + acc[nt][3] * d4.w;
    }
    ps += __shfl_xor(ps, 16); pd += __shfl_xor(pd, 16);
    ps += __shfl_xor(ps, 32); pd += __shfl_xor(pd, 32);
    if (q == 0) {
        als[rows_base + l16] = ps;
        ald[rows_base + l16] = pd;
    }

    __syncthreads();
    char* tb = (char*)Bs + wave * 4096;
    {
        int row = l16;
        unsigned key = (unsigned)(row & 7) << 4;
        #pragma unroll
        for (int nt = 0; nt < 8; ++nt) {
            ushort4 pk;
            pk.x = bf16_rne(acc[nt][0]);
            pk.y = bf16_rne(acc[nt][1]);
            pk.z = bf16_rne(acc[nt][2]);
            pk.w = bf16_rne(acc[nt][3]);
            unsigned byteoff = (unsigned)row * 256u + (unsigned)(nt * 16 + q * 4) * 2u;
            *(ushort4*)(tb + (byteoff ^ key)) = pk;
        }
    }
    __syncthreads();
    #pragma unroll
    for (int i = 0; i < 4; ++i) {
        int m = lane + 64 * i;
        unsigned row = (unsigned)m >> 4;
        unsigned byteoff = (unsigned)m * 16u;
        unsigned addr = byteoff ^ ((row & 7u) << 4);
        int4 v = *(const int4*)(tb + addr);
        *(int4*)((char*)Hb + (size_t)rows_base * 256 + (size_t)m * 16) = v;
    }
}

// ---------------- k_gemm: standalone GEMM for layers 1,2 (global fp32 A) ----------------

__global__ __launch_bounds__(256) void k_gemm(const float* __restrict__ A,
        const short* __restrict__ Whp, const short* __restrict__ Wlp,
        const float* __restrict__ a_s, const float* __restrict__ a_d,
        ushort_t* __restrict__ Hb, float* __restrict__ als, float* __restrict__ ald) {
    __shared__ int4 Bs[2048];
    int t = threadIdx.x;
    int wave = t >> 6, lane = t & 63;
    int l16 = lane & 15, q = lane >> 4;
    int rows_base = blockIdx.x * 64 + wave * 16;

    const int4* wh4 = (const int4*)Whp;
    const int4* wl4 = (const int4*)Wlp;
    const short* bsh = (const short*)Bs;
    const short* bsl = (const short*)(Bs + 1024);

    f32x4 acc[8] = {};
    #pragma unroll
    for (int h2 = 0; h2 < 2; ++h2) {
        if (h2) __syncthreads();
        #pragma unroll
        for (int i = 0; i < 4; ++i) {
            Bs[t + 256 * i] = wh4[h2 * 1024 + t + 256 * i];
            Bs[1024 + t + 256 * i] = wl4[h2 * 1024 + t + 256 * i];
        }
        __syncthreads();
        #pragma unroll
        for (int kk = 0; kk < 2; ++kk) {
            int ks = h2 * 2 + kk;
            const float* ap = A + (size_t)(rows_base + l16) * D + ks * 32 + q * 8;
            float4 v0 = *(const float4*)ap;
            float4 v1 = *(const float4*)(ap + 4);
            float f[8] = {v0.x, v0.y, v0.z, v0.w, v1.x, v1.y, v1.z, v1.w};
            bf16x8 ah, alo;
            #pragma unroll
            for (int j = 0; j < 8; ++j) {
                unsigned short hb = bf16_rne(f[j]);
                float hf = __uint_as_float(((unsigned)hb) << 16);
                ah[j]  = (short)hb;
                alo[j] = (short)bf16_rne(f[j] - hf);
            }
            #pragma unroll
            for (int nt = 0; nt < 8; ++nt) {
                int idx = (((kk * 4 + q) * 128) + nt * 16 + l16) * 8;
                bf16x8 bh = *(const bf16x8*)(bsh + idx);
                bf16x8 bl = *(const bf16x8*)(bsl + idx);
                acc[nt] = __builtin_amdgcn_mfma_f32_16x16x32_bf16(bh, ah, acc[nt], 0, 0, 0);
                acc[nt] = __builtin_amdgcn_mfma_f32_16x16x32_bf16(bl, ah, acc[nt], 0, 0, 0);
                acc[nt] = __builtin_amdgcn_mfma_f32_16x16x32_bf16(bh, alo, acc[nt], 0, 0, 0);
            }
        }
    }

    float ps = 0.f, pd = 0.f;
    #pragma unroll
    for (int nt = 0; nt < 8; ++nt) {
        float4 a4 = *(const float4*)(a_s + nt * 16 + q * 4);
        float4 d4 = *(const float4*)(a_d + nt * 16 + q * 4);
        ps += acc[nt][0] * a4.x + acc[nt][1] * a4.y + acc[nt][2] * a4.z + acc[nt][3] * a4.w;
        pd += acc[nt][0] * d4.x + acc[nt][1] * d4.y + acc[nt][2] * d4.z + acc[nt][3] * d4.w;
    }
    ps += __shfl_xor(ps, 16); pd += __shfl_xor(pd, 16);
    ps += __shfl_xor(ps, 32); pd += __shfl_xor(pd, 32);
    if (q == 0) {
        als[rows_base + l16] = ps;
        ald[rows_base + l16] = pd;
    }

    __syncthreads();
    char* tb = (char*)Bs + wave * 4096;
    {
        int row = l16;
        unsigned key = (unsigned)(row & 7) << 4;
        #pragma unroll
        for (int nt = 0; nt < 8; ++nt) {
            ushort4 pk;
            pk.x = bf16_rne(acc[nt][0]);
            pk.y = bf16_rne(acc[nt][1]);
            pk.z = bf16_rne(acc[nt][2]);
            pk.w = bf16_rne(acc[nt][3]);
            unsigned byteoff = (unsigned)row * 256u + (unsigned)(nt * 16 + q * 4) * 2u;
            *(ushort4*)(tb + (byteoff ^ key)) = pk;
        }
    }
    __syncthreads();
    #pragma unroll
    for (int i = 0; i < 4; ++i) {
        int m = lane + 64 * i;
        unsigned row = (unsigned)m >> 4;
        unsigned byteoff = (unsigned)m * 16u;
        unsigned addr = byteoff ^ ((row & 7u) << 4);
        int4 v = *(const int4*)(tb + addr);
        *(int4*)((char*)Hb + (size_t)rows_base * 256 + (size_t)m * 16) = v;
    }
}

// ---------------- k_aggr: fused softmax + gather, EARLY-ISSUE row loads ----------------
// 16 lanes per dst node. Fast path deg<=16: row gathers (which depend only on
// edata.x) are issued BEFORE the softmax shuffle chain, so up to 16x16B loads
// per lane are in flight while the reduction computes. Weights applied after.

__global__ __launch_bounds__(256) void k_aggr(const ushort_t* __restrict__ hb,
        const float* __restrict__ als, const float* __restrict__ ald,
        const int4* __restrict__ edata, const int* __restrict__ rp,
        const float* __restrict__ bias, int lsel, float* __restrict__ out_f32) {
    int t = threadIdx.x;
    int lane = t & 63;
    int l16 = lane & 15;
    int qb = lane & 48;                 // quarter base within wave
    int n = blockIdx.x * 16 + (t >> 4); // one node per 16 threads
    int s = rp[n], e = rp[n + 1];
    int deg = e - s;
    float aldd = ald[n];
    float alsn = als[n];
    float inv_deg = (deg > 0) ? 1.f / (float)deg : 0.f;

    int4 hvp = *(const int4*)(hb + (size_t)n * D + l16 * 8);
    float acc8[8];

    if (deg <= 16) {
        // -- load edge record + src attention (critical-path head) --
        int sn0 = 0;
        float alev0 = 0.f, alsg = 0.f;
        if (l16 < deg) {
            int4 ed = edata[s + l16];
            sn0 = ed.x;
            alev0 = __int_as_float((lsel == 0) ? ed.y : ((lsel == 1) ? ed.z : ed.w));
            alsg = als[sn0];
        }

        // -- broadcast src ids and ISSUE all row gathers now --
        int sA[8], sB[8];
        #pragma unroll
        for (int i = 0; i < 8; ++i) { sA[i] = __shfl(sn0, qb + i); sB[i] = __shfl(sn0, qb + 8 + i); }
        int4 rb[8];
        #pragma unroll
        for (int i = 0; i < 8; ++i) rb[i] = *(const int4*)(hb + (size_t)sA[i] * D + l16 * 8);
        bool more = (deg > 8);
        int4 rb2[8];
        if (more) {
            #pragma unroll
            for (int i = 0; i < 8; ++i) rb2[i] = *(const int4*)(hb + (size_t)sB[i] * D + l16 * 8);
        }

        // -- softmax reduction runs while gathers are in flight --
        float al0 = (l16 < deg) ? leaky(alsg + aldd + alev0) : -1e30f;
        float mm = al0, asum = alev0;
        #pragma unroll
        for (int off = 1; off < 16; off <<= 1) {
            mm = fmaxf(mm, __shfl_xor(mm, off));
            asum += __shfl_xor(asum, off);
        }
        float self_al = leaky(alsn + aldd + asum * inv_deg);
        mm = fmaxf(mm, self_al);
        float p0 = (l16 < deg) ? __expf(al0 - mm) : 0.f;
        float den = p0;
        #pragma unroll
        for (int off = 1; off < 16; off <<= 1) den += __shfl_xor(den, off);
        float es = __expf(self_al - mm);
        den += es;
        float inv = 1.f / den;
        float w0 = p0 * inv;       // exactly 0 for l16 >= deg
        float wself = es * inv;

        float fv[8];
        unpack8(hvp, fv);
        #pragma unroll
        for (int j = 0; j < 8; ++j) acc8[j] = wself * fv[j];

        float wA[8], wB[8];
        #pragma unroll
        for (int i = 0; i < 8; ++i) { wA[i] = __shfl(w0, qb + i); wB[i] = __shfl(w0, qb + 8 + i); }

        #pragma unroll
        for (int i = 0; i < 8; ++i) {
            float f[8];
            unpack8(rb[i], f);
            #pragma unroll
            for (int j = 0; j < 8; ++j) acc8[j] += wA[i] * f[j];
        }
        if (more) {
            #pragma unroll
            for (int i = 0; i < 8; ++i) {
                float f[8];
                unpack8(rb2[i], f);
                #pragma unroll
                for (int j = 0; j < 8; ++j) acc8[j] += wB[i] * f[j];
            }
        }
    } else {
        // general path (rare): chunked 3-pass with recompute
        float mm = -1e30f, asum = 0.f;
        for (int base = s; base < e; base += 16) {
            int j = base + l16;
            if (j < e) {
                int4 ed = edata[j];
                float alev = __int_as_float((lsel == 0) ? ed.y : ((lsel == 1) ? ed.z : ed.w));
                asum += alev;
                mm = fmaxf(mm, leaky(als[ed.x] + aldd + alev));
            }
        }
        #pragma unroll
        for (int off = 1; off < 16; off <<= 1) {
            mm = fmaxf(mm, __shfl_xor(mm, off));
            asum += __shfl_xor(asum, off);
        }
        float self_al = leaky(alsn + aldd + asum * inv_deg);
        mm = fmaxf(mm, self_al);
        float den = 0.f;
        for (int base = s; base < e; base += 16) {
            int j = base + l16;
            if (j < e) {
                int4 ed = edata[j];
                float alev = __int_as_float((lsel == 0) ? ed.y : ((lsel == 1) ? ed.z : ed.w));
                den += __expf(leaky(als[ed.x] + aldd + alev) - mm);
            }
        }
        #pragma unroll
        for (int off = 1; off < 16; off <<= 1) den += __shfl_xor(den, off);
        float es = __expf(self_al - mm);
        den += es;
        float inv = 1.f / den;
        float wself = es * inv;
        float fv[8];
        unpack8(hvp, fv);
        #pragma unroll
        for (int j = 0; j < 8; ++j) acc8[j] = wself * fv[j];
        for (int base = s; base < e; base += 16) {
            int cnt = min(e - base, 16);
            int sn = 0;
            float w = 0.f;
            if (l16 < cnt) {
                int4 ed = edata[base + l16];
                sn = ed.x;
                float alev = __int_as_float((lsel == 0) ? ed.y : ((lsel == 1) ? ed.z : ed.w));
                w = __expf(leaky(als[sn] + aldd + alev) - mm) * inv;
            }
            for (int tt = 0; tt < cnt; ++tt) {
                int st = __shfl(sn, qb + tt);
                float wt = __shfl(w, qb + tt);
                int4 r = *(const int4*)(hb + (size_t)st * D + l16 * 8);
                float f[8];
                unpack8(r, f);
                #pragma unroll
                for (int j = 0; j < 8; ++j) acc8[j] += wt * f[j];
            }
        }
    }

    const float4* b4 = (const float4*)(bias + l16 * 8);
    float4 b0 = b4[0], b1 = b4[1];
    float bb[8] = {b0.x, b0.y, b0.z, b0.w, b1.x, b1.y, b1.z, b1.w};
    float o[8];
    #pragma unroll
    for (int j = 0; j < 8; ++j) o[j] = gelu_exact(acc8[j] + bb[j]);

    float4* o4 = (float4*)(out_f32 + (size_t)n * D + l16 * 8);
    o4[0] = make_float4(o[0], o[1], o[2], o[3]);
    o4[1] = make_float4(o[4], o[5], o[6], o[7]);
}

// ---------------- launch ----------------

extern "C" void kernel_launch(void* const* d_in, const int* in_sizes, int n_in,
                              void* d_out, int out_size, void* d_ws, size_t ws_size,
                              hipStream_t stream) {
    (void)in_sizes; (void)n_in; (void)out_size; (void)ws_size;
    const float* x        = (const float*)d_in[0];
    const int*   eidx     = (const int*)d_in[1];   // [2, NE]: row0=src, row1=dst
    const float* ea       = (const float*)d_in[2];
    const float* Ws       = (const float*)d_in[3];
    const float* att_src  = (const float*)d_in[4];
    const float* att_dst  = (const float*)d_in[5];
    const float* W_edge   = (const float*)d_in[6];
    const float* att_edge = (const float*)d_in[7];
    const float* bias     = (const float*)d_in[8];
    float* out = (float*)d_out;

    char* ws = (char*)d_ws;
    size_t off = 0;
    auto alloc = [&](size_t bytes) {
        void* p = ws + off;
        off += (bytes + 255) & ~(size_t)255;
        return p;
    };
    ushort_t* Hb   = (ushort_t*)alloc((size_t)NN * D * 2);  // bf16 h after GEMM (gather input)
    float*    Hx   = (float*)alloc((size_t)NN * D * 4);     // fp32 activations between layers
    float*    als  = (float*)alloc((size_t)NN * 4);
    float*    ald  = (float*)alloc((size_t)NN * 4);
    int4*     edata= (int4*)alloc((size_t)(NE + 16) * 16);  // (src, ale0, ale1, ale2)
    float*    ale0 = (float*)alloc((size_t)NE * 4);
    float*    ale1 = (float*)alloc((size_t)NE * 4);
    float*    ale2 = (float*)alloc((size_t)NE * 4);
    int*      deg  = (int*)alloc((size_t)NN * 4);
    int*      rp   = (int*)alloc((size_t)(NN + 4) * 4);
    int*      cursor = (int*)alloc((size_t)NN * 4);
    int*      bsum = (int*)alloc(256 * 4);
    short*    Whp  = (short*)alloc((size_t)3 * D * D * 2);
    short*    Wlp  = (short*)alloc((size_t)3 * D * D * 2);

    const int* e_src = eidx;
    const int* e_dst = eidx + NE;

    // CSR build + edge precompute + weight pack (fused front)
    hipMemsetAsync(deg, 0, (size_t)NN * 4, stream);
    k_front<<<NE / 256 + 24, 256, 0, stream>>>(ea, e_dst, deg, W_edge, att_edge,
                                               Ws, Whp, Wlp, ale0, ale1, ale2);
    k_scan1<<<NN / 256, 256, 0, stream>>>(deg, rp, bsum);
    k_scanF<<<NN / 256, 256, 0, stream>>>(rp, bsum, cursor);

    // k0: layer-0 GEMM + fused scatter
    k_gemm0scat<<<NN / 64, 256, 0, stream>>>(x, Whp, Wlp, att_src, att_dst,
                                             Hb, als, ald,
                                             e_src, e_dst, cursor, ale0, ale1, ale2, edata);

    // layers: aggr(l) -> gemm(l+1), final aggr writes out
    for (int l = 0; l < 3; ++l) {
        bool last = (l == 2);
        k_aggr<<<NN / 16, 256, 0, stream>>>(Hb, als, ald, edata, rp, bias + (size_t)l * D, l,
                                            last ? out : Hx);
        if (!last) {
            k_gemm<<<NN / 64, 256, 0, stream>>>(Hx, Whp + (size_t)(l + 1) * D * D,
                                                Wlp + (size_t)(l + 1) * D * D,
                                                att_src + (size_t)(l + 1) * D,
                                                att_dst + (size_t)(l + 1) * D,
                                                Hb, als, ald);
        }
    }
}

// Round 5
// 343.808 us; speedup vs baseline: 1.0527x; 1.0238x over previous
//
#include <hip/hip_runtime.h>
#include <math.h>

#define NN 65536        // nodes
#define NE 524288       // edges (without self loops)
#define D 128
#define ED 32
#define NEG_SLOPE 0.2f

typedef short bf16x8 __attribute__((ext_vector_type(8)));
typedef float f32x4 __attribute__((ext_vector_type(4)));
typedef unsigned short ushort_t;

__device__ __forceinline__ float leaky(float x) { return x > 0.f ? x : NEG_SLOPE * x; }
__device__ __forceinline__ float gelu_exact(float x) {
    return 0.5f * x * (1.f + erff(x * 0.70710678118654752440f));
}
__device__ __forceinline__ unsigned short bf16_rne(float x) {
    unsigned u = __float_as_uint(x);
    return (unsigned short)((u + 0x7FFFu + ((u >> 16) & 1u)) >> 16);
}
__device__ __forceinline__ void unpack8(int4 r, float* f) {
    unsigned u0 = (unsigned)r.x, u1 = (unsigned)r.y, u2 = (unsigned)r.z, u3 = (unsigned)r.w;
    f[0] = __uint_as_float(u0 << 16); f[1] = __uint_as_float(u0 & 0xFFFF0000u);
    f[2] = __uint_as_float(u1 << 16); f[3] = __uint_as_float(u1 & 0xFFFF0000u);
    f[4] = __uint_as_float(u2 << 16); f[5] = __uint_as_float(u2 & 0xFFFF0000u);
    f[6] = __uint_as_float(u3 << 16); f[7] = __uint_as_float(u3 & 0xFFFF0000u);
}

// ---------------- front: fused {ale_hist (wvec inline) | wpack} ----------------
// ale role ALSO: (a) stores edge rank (atomicAdd return) -> later scatter is
// atomic-free; (b) packs (src, ale0, ale1, ale2) as one int4 in edge order.

__global__ __launch_bounds__(256) void k_front(const float* __restrict__ ea,
        const int* __restrict__ srcArr, const int* __restrict__ dstArr,
        int* __restrict__ deg, int* __restrict__ rankArr,
        const float* __restrict__ We, const float* __restrict__ ae,
        const float* __restrict__ Ws, short* __restrict__ Whp, short* __restrict__ Wlp,
        int4* __restrict__ edata_eo) {
    if (blockIdx.x >= NE / 256) {
        // ---- wpack role: pack W into MFMA fragment order, split bf16 hi/lo ----
        int t = (blockIdx.x - NE / 256) * 256 + threadIdx.x;
        if (t >= 3 * 4 * 4 * 128) return;
        int n = t & 127;
        int q = (t >> 7) & 3;
        int ks = (t >> 9) & 3;
        int l = t >> 11;
        const float* w = Ws + (size_t)l * D * D;
        size_t obase = (size_t)l * D * D + ((size_t)((ks * 4 + q) * 128) + n) * 8;
        #pragma unroll
        for (int j = 0; j < 8; ++j) {
            float x = w[(size_t)(ks * 32 + q * 8 + j) * D + n];
            unsigned short hb = bf16_rne(x);
            float hf = __uint_as_float(((unsigned)hb) << 16);
            Whp[obase + j] = (short)hb;
            Wlp[obase + j] = (short)bf16_rne(x - hf);
        }
        return;
    }
    // ---- ale role ----
    __shared__ __align__(16) float wv[3 * ED];
    int t = threadIdx.x;
    if (t < 3 * ED) {
        int l = t >> 5, k = t & 31;
        const float4* w = (const float4*)(We + (size_t)(l * ED + k) * D);
        const float4* a = (const float4*)(ae + (size_t)l * D);
        float s = 0.f;
        #pragma unroll
        for (int i = 0; i < D / 4; ++i) {
            float4 x = w[i], y = a[i];
            s += x.x * y.x + x.y * y.y + x.z * y.z + x.w * y.w;
        }
        wv[t] = s;
    }
    __syncthreads();
    int e = blockIdx.x * 256 + t;
    int rank = atomicAdd(&deg[dstArr[e]], 1);
    rankArr[e] = rank;
    const float4* row = (const float4*)(ea + (size_t)e * ED);
    const float4* w0 = (const float4*)(wv);
    const float4* w1 = (const float4*)(wv + ED);
    const float4* w2 = (const float4*)(wv + 2 * ED);
    float s0 = 0.f, s1 = 0.f, s2 = 0.f;
    #pragma unroll
    for (int i = 0; i < ED / 4; ++i) {
        float4 v = row[i];
        float4 a = w0[i], b = w1[i], c = w2[i];
        s0 += v.x * a.x + v.y * a.y + v.z * a.z + v.w * a.w;
        s1 += v.x * b.x + v.y * b.y + v.z * b.z + v.w * b.w;
        s2 += v.x * c.x + v.y * c.y + v.z * c.z + v.w * c.w;
    }
    edata_eo[e] = make_int4(srcArr[e], __float_as_int(s0), __float_as_int(s1), __float_as_int(s2));
}

// ---------------- scan (2 kernels) ----------------

__global__ void k_scan1(const int* __restrict__ deg, int* __restrict__ rp, int* __restrict__ bsum) {
    __shared__ int s[256];
    int t = threadIdx.x;
    int i = blockIdx.x * 256 + t;
    int v = deg[i];
    s[t] = v;
    __syncthreads();
    #pragma unroll
    for (int off = 1; off < 256; off <<= 1) {
        int x = (t >= off) ? s[t - off] : 0;
        __syncthreads();
        s[t] += x;
        __syncthreads();
    }
    rp[i] = s[t] - v;
    if (t == 255) bsum[blockIdx.x] = s[t];
}

__global__ void k_scanF(int* __restrict__ rp, const int* __restrict__ bsum) {
    __shared__ int s[256];
    int t = threadIdx.x;
    int bid = blockIdx.x;
    int v = bsum[t];
    s[t] = v;
    __syncthreads();
    #pragma unroll
    for (int off = 1; off < 256; off <<= 1) {
        int x = (t >= off) ? s[t - off] : 0;
        __syncthreads();
        s[t] += x;
        __syncthreads();
    }
    int add = (bid > 0) ? s[bid - 1] : 0;
    int i = bid * 256 + t;
    rp[i] += add;
    if (bid == 255 && t == 255) rp[NN] = NE;
}

// ---------------- k0: layer-0 GEMM (global A = x) + fused ATOMIC-FREE scatter ----------------
// Every block owns a 64-row gemm tile AND a 512-edge scatter slice.
// Scatter position p = rp[dst] + rank (rank from k_front's histogram), so the
// prologue is pure loads + stores; stores drain under the MFMA loop.

__global__ __launch_bounds__(256) void k_gemm0scat(const float* __restrict__ A,
        const short* __restrict__ Whp, const short* __restrict__ Wlp,
        const float* __restrict__ a_s, const float* __restrict__ a_d,
        ushort_t* __restrict__ Hb, float* __restrict__ als, float* __restrict__ ald,
        const int* __restrict__ dstArr, const int* __restrict__ rankArr,
        const int* __restrict__ rp, const int4* __restrict__ edata_eo,
        int4* __restrict__ edata) {
    __shared__ int4 Bs[2048];   // 32KB: [0..1023]=hi, [1024..2047]=lo; reused for transpose
    int t = threadIdx.x;
    int wave = t >> 6, lane = t & 63;
    int l16 = lane & 15, q = lane >> 4;
    int b = blockIdx.x;
    int rows_base = b * 64 + wave * 16;

    // ---- scatter: 2 edges per thread, no atomics; stores fire-and-forget ----
    {
        int e0 = b * 512 + t, e1 = e0 + 256;
        int d0 = dstArr[e0], d1 = dstArr[e1];
        int r0 = rankArr[e0], r1 = rankArr[e1];
        int4 rec0 = edata_eo[e0], rec1 = edata_eo[e1];
        int p0 = rp[d0] + r0;
        int p1 = rp[d1] + r1;
        edata[p0] = rec0;
        edata[p1] = rec1;
    }

    const int4* wh4 = (const int4*)Whp;
    const int4* wl4 = (const int4*)Wlp;
    const short* bsh = (const short*)Bs;
    const short* bsl = (const short*)(Bs + 1024);

    f32x4 acc[8] = {};
    #pragma unroll
    for (int h2 = 0; h2 < 2; ++h2) {
        if (h2) __syncthreads();
        #pragma unroll
        for (int i = 0; i < 4; ++i) {
            Bs[t + 256 * i] = wh4[h2 * 1024 + t + 256 * i];
            Bs[1024 + t + 256 * i] = wl4[h2 * 1024 + t + 256 * i];
        }
        __syncthreads();
        #pragma unroll
        for (int kk = 0; kk < 2; ++kk) {
            int ks = h2 * 2 + kk;
            const float* ap = A + (size_t)(rows_base + l16) * D + ks * 32 + q * 8;
            float4 v0 = *(const float4*)ap;
            float4 v1 = *(const float4*)(ap + 4);
            float f[8] = {v0.x, v0.y, v0.z, v0.w, v1.x, v1.y, v1.z, v1.w};
            bf16x8 ah, alo;
            #pragma unroll
            for (int j = 0; j < 8; ++j) {
                unsigned short hb = bf16_rne(f[j]);
                float hf = __uint_as_float(((unsigned)hb) << 16);
                ah[j]  = (short)hb;
                alo[j] = (short)bf16_rne(f[j] - hf);
            }
            #pragma unroll
            for (int nt = 0; nt < 8; ++nt) {
                int idx = (((kk * 4 + q) * 128) + nt * 16 + l16) * 8;
                bf16x8 bh = *(const bf16x8*)(bsh + idx);
                bf16x8 bl = *(const bf16x8*)(bsl + idx);
                acc[nt] = __builtin_amdgcn_mfma_f32_16x16x32_bf16(bh, ah, acc[nt], 0, 0, 0);
                acc[nt] = __builtin_amdgcn_mfma_f32_16x16x32_bf16(bl, ah, acc[nt], 0, 0, 0);
                acc[nt] = __builtin_amdgcn_mfma_f32_16x16x32_bf16(bh, alo, acc[nt], 0, 0, 0);
            }
        }
    }

    // ---- epilogue: als/ald + Hb via swizzled LDS transpose ----
    float ps = 0.f, pd = 0.f;
    #pragma unroll
    for (int nt = 0; nt < 8; ++nt) {
        float4 a4 = *(const float4*)(a_s + nt * 16 + q * 4);
        float4 d4 = *(const float4*)(a_d + nt * 16 + q * 4);
        ps += acc[nt][0] * a4.x + acc[nt][1] * a4.y + acc[nt][2] * a4.z + acc[nt][3] * a4.w;
        pd += acc[nt][0] * d4.x + acc[nt][1] * d4.y + acc[nt][2] * d4.z + acc[nt][3] * d4.w;
    }
    ps += __shfl_xor(ps, 16); pd += __shfl_xor(pd, 16);
    ps += __shfl_xor(ps, 32); pd += __shfl_xor(pd, 32);
    if (q == 0) {
        als[rows_base + l16] = ps;
        ald[rows_base + l16] = pd;
    }

    __syncthreads();
    char* tb = (char*)Bs + wave * 4096;
    {
        int row = l16;
        unsigned key = (unsigned)(row & 7) << 4;
        #pragma unroll
        for (int nt = 0; nt < 8; ++nt) {
            ushort4 pk;
            pk.x = bf16_rne(acc[nt][0]);
            pk.y = bf16_rne(acc[nt][1]);
            pk.z = bf16_rne(acc[nt][2]);
            pk.w = bf16_rne(acc[nt][3]);
            unsigned byteoff = (unsigned)row * 256u + (unsigned)(nt * 16 + q * 4) * 2u;
            *(ushort4*)(tb + (byteoff ^ key)) = pk;
        }
    }
    __syncthreads();
    #pragma unroll
    for (int i = 0; i < 4; ++i) {
        int m = lane + 64 * i;
        unsigned row = (unsigned)m >> 4;
        unsigned byteoff = (unsigned)m * 16u;
        unsigned addr = byteoff ^ ((row & 7u) << 4);
        int4 v = *(const int4*)(tb + addr);
        *(int4*)((char*)Hb + (size_t)rows_base * 256 + (size_t)m * 16) = v;
    }
}

// ---------------- k_gemm: standalone GEMM for layers 1,2 (global fp32 A) ----------------

__global__ __launch_bounds__(256) void k_gemm(const float* __restrict__ A,
        const short* __restrict__ Whp, const short* __restrict__ Wlp,
        const float* __restrict__ a_s, const float* __restrict__ a_d,
        ushort_t* __restrict__ Hb, float* __restrict__ als, float* __restrict__ ald) {
    __shared__ int4 Bs[2048];
    int t = threadIdx.x;
    int wave = t >> 6, lane = t & 63;
    int l16 = lane & 15, q = lane >> 4;
    int rows_base = blockIdx.x * 64 + wave * 16;

    const int4* wh4 = (const int4*)Whp;
    const int4* wl4 = (const int4*)Wlp;
    const short* bsh = (const short*)Bs;
    const short* bsl = (const short*)(Bs + 1024);

    f32x4 acc[8] = {};
    #pragma unroll
    for (int h2 = 0; h2 < 2; ++h2) {
        if (h2) __syncthreads();
        #pragma unroll
        for (int i = 0; i < 4; ++i) {
            Bs[t + 256 * i] = wh4[h2 * 1024 + t + 256 * i];
            Bs[1024 + t + 256 * i] = wl4[h2 * 1024 + t + 256 * i];
        }
        __syncthreads();
        #pragma unroll
        for (int kk = 0; kk < 2; ++kk) {
            int ks = h2 * 2 + kk;
            const float* ap = A + (size_t)(rows_base + l16) * D + ks * 32 + q * 8;
            float4 v0 = *(const float4*)ap;
            float4 v1 = *(const float4*)(ap + 4);
            float f[8] = {v0.x, v0.y, v0.z, v0.w, v1.x, v1.y, v1.z, v1.w};
            bf16x8 ah, alo;
            #pragma unroll
            for (int j = 0; j < 8; ++j) {
                unsigned short hb = bf16_rne(f[j]);
                float hf = __uint_as_float(((unsigned)hb) << 16);
                ah[j]  = (short)hb;
                alo[j] = (short)bf16_rne(f[j] - hf);
            }
            #pragma unroll
            for (int nt = 0; nt < 8; ++nt) {
                int idx = (((kk * 4 + q) * 128) + nt * 16 + l16) * 8;
                bf16x8 bh = *(const bf16x8*)(bsh + idx);
                bf16x8 bl = *(const bf16x8*)(bsl + idx);
                acc[nt] = __builtin_amdgcn_mfma_f32_16x16x32_bf16(bh, ah, acc[nt], 0, 0, 0);
                acc[nt] = __builtin_amdgcn_mfma_f32_16x16x32_bf16(bl, ah, acc[nt], 0, 0, 0);
                acc[nt] = __builtin_amdgcn_mfma_f32_16x16x32_bf16(bh, alo, acc[nt], 0, 0, 0);
            }
        }
    }

    float ps = 0.f, pd = 0.f;
    #pragma unroll
    for (int nt = 0; nt < 8; ++nt) {
        float4 a4 = *(const float4*)(a_s + nt * 16 + q * 4);
        float4 d4 = *(const float4*)(a_d + nt * 16 + q * 4);
        ps += acc[nt][0] * a4.x + acc[nt][1] * a4.y + acc[nt][2] * a4.z + acc[nt][3] * a4.w;
        pd += acc[nt][0] * d4.x + acc[nt][1] * d4.y + acc[nt][2] * d4.z + acc[nt][3] * d4.w;
    }
    ps += __shfl_xor(ps, 16); pd += __shfl_xor(pd, 16);
    ps += __shfl_xor(ps, 32); pd += __shfl_xor(pd, 32);
    if (q == 0) {
        als[rows_base + l16] = ps;
        ald[rows_base + l16] = pd;
    }

    __syncthreads();
    char* tb = (char*)Bs + wave * 4096;
    {
        int row = l16;
        unsigned key = (unsigned)(row & 7) << 4;
        #pragma unroll
        for (int nt = 0; nt < 8; ++nt) {
            ushort4 pk;
            pk.x = bf16_rne(acc[nt][0]);
            pk.y = bf16_rne(acc[nt][1]);
            pk.z = bf16_rne(acc[nt][2]);
            pk.w = bf16_rne(acc[nt][3]);
            unsigned byteoff = (unsigned)row * 256u + (unsigned)(nt * 16 + q * 4) * 2u;
            *(ushort4*)(tb + (byteoff ^ key)) = pk;
        }
    }
    __syncthreads();
    #pragma unroll
    for (int i = 0; i < 4; ++i) {
        int m = lane + 64 * i;
        unsigned row = (unsigned)m >> 4;
        unsigned byteoff = (unsigned)m * 16u;
        unsigned addr = byteoff ^ ((row & 7u) << 4);
        int4 v = *(const int4*)(tb + addr);
        *(int4*)((char*)Hb + (size_t)rows_base * 256 + (size_t)m * 16) = v;
    }
}

// ---------------- k_aggr: fused softmax + gather, early-issue row loads ----------------

__global__ __launch_bounds__(256) void k_aggr(const ushort_t* __restrict__ hb,
        const float* __restrict__ als, const float* __restrict__ ald,
        const int4* __restrict__ edata, const int* __restrict__ rp,
        const float* __restrict__ bias, int lsel, float* __restrict__ out_f32) {
    int t = threadIdx.x;
    int lane = t & 63;
    int l16 = lane & 15;
    int qb = lane & 48;                 // quarter base within wave
    int n = blockIdx.x * 16 + (t >> 4); // one node per 16 threads
    int s = rp[n], e = rp[n + 1];
    int deg = e - s;
    float aldd = ald[n];
    float alsn = als[n];
    float inv_deg = (deg > 0) ? 1.f / (float)deg : 0.f;

    int4 hvp = *(const int4*)(hb + (size_t)n * D + l16 * 8);
    float acc8[8];

    if (deg <= 16) {
        // -- load edge record + src attention (critical-path head) --
        int sn0 = 0;
        float alev0 = 0.f, alsg = 0.f;
        if (l16 < deg) {
            int4 ed = edata[s + l16];
            sn0 = ed.x;
            alev0 = __int_as_float((lsel == 0) ? ed.y : ((lsel == 1) ? ed.z : ed.w));
            alsg = als[sn0];
        }

        // -- broadcast src ids and ISSUE all row gathers now --
        int sA[8], sB[8];
        #pragma unroll
        for (int i = 0; i < 8; ++i) { sA[i] = __shfl(sn0, qb + i); sB[i] = __shfl(sn0, qb + 8 + i); }
        int4 rb[8];
        #pragma unroll
        for (int i = 0; i < 8; ++i) rb[i] = *(const int4*)(hb + (size_t)sA[i] * D + l16 * 8);
        bool more = (deg > 8);
        int4 rb2[8];
        if (more) {
            #pragma unroll
            for (int i = 0; i < 8; ++i) rb2[i] = *(const int4*)(hb + (size_t)sB[i] * D + l16 * 8);
        }

        // -- softmax reduction runs while gathers are in flight --
        float al0 = (l16 < deg) ? leaky(alsg + aldd + alev0) : -1e30f;
        float mm = al0, asum = alev0;
        #pragma unroll
        for (int off = 1; off < 16; off <<= 1) {
            mm = fmaxf(mm, __shfl_xor(mm, off));
            asum += __shfl_xor(asum, off);
        }
        float self_al = leaky(alsn + aldd + asum * inv_deg);
        mm = fmaxf(mm, self_al);
        float p0 = (l16 < deg) ? __expf(al0 - mm) : 0.f;
        float den = p0;
        #pragma unroll
        for (int off = 1; off < 16; off <<= 1) den += __shfl_xor(den, off);
        float es = __expf(self_al - mm);
        den += es;
        float inv = 1.f / den;
        float w0 = p0 * inv;       // exactly 0 for l16 >= deg
        float wself = es * inv;

        float fv[8];
        unpack8(hvp, fv);
        #pragma unroll
        for (int j = 0; j < 8; ++j) acc8[j] = wself * fv[j];

        float wA[8], wB[8];
        #pragma unroll
        for (int i = 0; i < 8; ++i) { wA[i] = __shfl(w0, qb + i); wB[i] = __shfl(w0, qb + 8 + i); }

        #pragma unroll
        for (int i = 0; i < 8; ++i) {
            float f[8];
            unpack8(rb[i], f);
            #pragma unroll
            for (int j = 0; j < 8; ++j) acc8[j] += wA[i] * f[j];
        }
        if (more) {
            #pragma unroll
            for (int i = 0; i < 8; ++i) {
                float f[8];
                unpack8(rb2[i], f);
                #pragma unroll
                for (int j = 0; j < 8; ++j) acc8[j] += wB[i] * f[j];
            }
        }
    } else {
        // general path (rare): chunked 3-pass with recompute
        float mm = -1e30f, asum = 0.f;
        for (int base = s; base < e; base += 16) {
            int j = base + l16;
            if (j < e) {
                int4 ed = edata[j];
                float alev = __int_as_float((lsel == 0) ? ed.y : ((lsel == 1) ? ed.z : ed.w));
                asum += alev;
                mm = fmaxf(mm, leaky(als[ed.x] + aldd + alev));
            }
        }
        #pragma unroll
        for (int off = 1; off < 16; off <<= 1) {
            mm = fmaxf(mm, __shfl_xor(mm, off));
            asum += __shfl_xor(asum, off);
        }
        float self_al = leaky(alsn + aldd + asum * inv_deg);
        mm = fmaxf(mm, self_al);
        float den = 0.f;
        for (int base = s; base < e; base += 16) {
            int j = base + l16;
            if (j < e) {
                int4 ed = edata[j];
                float alev = __int_as_float((lsel == 0) ? ed.y : ((lsel == 1) ? ed.z : ed.w));
                den += __expf(leaky(als[ed.x] + aldd + alev) - mm);
            }
        }
        #pragma unroll
        for (int off = 1; off < 16; off <<= 1) den += __shfl_xor(den, off);
        float es = __expf(self_al - mm);
        den += es;
        float inv = 1.f / den;
        float wself = es * inv;
        float fv[8];
        unpack8(hvp, fv);
        #pragma unroll
        for (int j = 0; j < 8; ++j) acc8[j] = wself * fv[j];
        for (int base = s; base < e; base += 16) {
            int cnt = min(e - base, 16);
            int sn = 0;
            float w = 0.f;
            if (l16 < cnt) {
                int4 ed = edata[base + l16];
                sn = ed.x;
                float alev = __int_as_float((lsel == 0) ? ed.y : ((lsel == 1) ? ed.z : ed.w));
                w = __expf(leaky(als[sn] + aldd + alev) - mm) * inv;
            }
            for (int tt = 0; tt < cnt; ++tt) {
                int st = __shfl(sn, qb + tt);
                float wt = __shfl(w, qb + tt);
                int4 r = *(const int4*)(hb + (size_t)st * D + l16 * 8);
                float f[8];
                unpack8(r, f);
                #pragma unroll
                for (int j = 0; j < 8; ++j) acc8[j] += wt * f[j];
            }
        }
    }

    const float4* b4 = (const float4*)(bias + l16 * 8);
    float4 b0 = b4[0], b1 = b4[1];
    float bb[8] = {b0.x, b0.y, b0.z, b0.w, b1.x, b1.y, b1.z, b1.w};
    float o[8];
    #pragma unroll
    for (int j = 0; j < 8; ++j) o[j] = gelu_exact(acc8[j] + bb[j]);

    float4* o4 = (float4*)(out_f32 + (size_t)n * D + l16 * 8);
    o4[0] = make_float4(o[0], o[1], o[2], o[3]);
    o4[1] = make_float4(o[4], o[5], o[6], o[7]);
}

// ---------------- launch ----------------

extern "C" void kernel_launch(void* const* d_in, const int* in_sizes, int n_in,
                              void* d_out, int out_size, void* d_ws, size_t ws_size,
                              hipStream_t stream) {
    (void)in_sizes; (void)n_in; (void)out_size; (void)ws_size;
    const float* x        = (const float*)d_in[0];
    const int*   eidx     = (const int*)d_in[1];   // [2, NE]: row0=src, row1=dst
    const float* ea       = (const float*)d_in[2];
    const float* Ws       = (const float*)d_in[3];
    const float* att_src  = (const float*)d_in[4];
    const float* att_dst  = (const float*)d_in[5];
    const float* W_edge   = (const float*)d_in[6];
    const float* att_edge = (const float*)d_in[7];
    const float* bias     = (const float*)d_in[8];
    float* out = (float*)d_out;

    char* ws = (char*)d_ws;
    size_t off = 0;
    auto alloc = [&](size_t bytes) {
        void* p = ws + off;
        off += (bytes + 255) & ~(size_t)255;
        return p;
    };
    ushort_t* Hb   = (ushort_t*)alloc((size_t)NN * D * 2);  // bf16 h after GEMM (gather input)
    float*    Hx   = (float*)alloc((size_t)NN * D * 4);     // fp32 activations between layers
    float*    als  = (float*)alloc((size_t)NN * 4);
    float*    ald  = (float*)alloc((size_t)NN * 4);
    int4*     edata= (int4*)alloc((size_t)(NE + 16) * 16);  // CSR-order (src, ale0, ale1, ale2)
    int4*     edata_eo = (int4*)alloc((size_t)NE * 16);     // edge-order records
    int*      rankArr = (int*)alloc((size_t)NE * 4);        // rank within dst segment
    int*      deg  = (int*)alloc((size_t)NN * 4);
    int*      rp   = (int*)alloc((size_t)(NN + 4) * 4);
    int*      bsum = (int*)alloc(256 * 4);
    short*    Whp  = (short*)alloc((size_t)3 * D * D * 2);
    short*    Wlp  = (short*)alloc((size_t)3 * D * D * 2);

    const int* e_src = eidx;
    const int* e_dst = eidx + NE;

    // CSR build + edge precompute + weight pack (fused front)
    hipMemsetAsync(deg, 0, (size_t)NN * 4, stream);
    k_front<<<NE / 256 + 24, 256, 0, stream>>>(ea, e_src, e_dst, deg, rankArr,
                                               W_edge, att_edge, Ws, Whp, Wlp, edata_eo);
    k_scan1<<<NN / 256, 256, 0, stream>>>(deg, rp, bsum);
    k_scanF<<<NN / 256, 256, 0, stream>>>(rp, bsum);

    // k0: layer-0 GEMM + fused atomic-free scatter
    k_gemm0scat<<<NN / 64, 256, 0, stream>>>(x, Whp, Wlp, att_src, att_dst,
                                             Hb, als, ald,
                                             e_dst, rankArr, rp, edata_eo, edata);

    // layers: aggr(l) -> gemm(l+1), final aggr writes out
    for (int l = 0; l < 3; ++l) {
        bool last = (l == 2);
        k_aggr<<<NN / 16, 256, 0, stream>>>(Hb, als, ald, edata, rp, bias + (size_t)l * D, l,
                                            last ? out : Hx);
        if (!last) {
            k_gemm<<<NN / 64, 256, 0, stream>>>(Hx, Whp + (size_t)(l + 1) * D * D,
                                                Wlp + (size_t)(l + 1) * D * D,
                                                att_src + (size_t)(l + 1) * D,
                                                att_dst + (size_t)(l + 1) * D,
                                                Hb, als, ald);
        }
    }
}